// Round 1
// baseline (428.132 us; speedup 1.0000x reference)
//
#include <hip/hip_runtime.h>
#include <math.h>

// Problem constants (match reference)
#define LQ     1024          // sequence length
#define BQ     256           // batch
#define NFRAG  32            // sqrt(LQ)
#define NKMER  10648         // 22^3
#define HID    64

// ---------- small float3 helpers ----------
__device__ __forceinline__ float3 f3sub(float3 a, float3 b) {
    return make_float3(a.x - b.x, a.y - b.y, a.z - b.z);
}
__device__ __forceinline__ float3 f3cross(float3 a, float3 b) {
    return make_float3(a.y * b.z - a.z * b.y,
                       a.z * b.x - a.x * b.z,
                       a.x * b.y - a.y * b.x);
}
__device__ __forceinline__ float3 f3norm(float3 v) {
    float n   = sqrtf(v.x * v.x + v.y * v.y + v.z * v.z);
    float inv = 1.0f / fmaxf(n, 1e-12f);
    return make_float3(v.x * inv, v.y * inv, v.z * inv);
}

// ---------- Table precompute kernels ----------
// seqTable[r][j] = sum_k seq_embed[r][k]*W0[k][j] + b0[j]   (20 x 64)
__global__ __launch_bounds__(64) void seq_table_kernel(
    const float* __restrict__ se, const float* __restrict__ W0,
    const float* __restrict__ b0, float* __restrict__ seqT) {
    int j = threadIdx.x;
    int r = blockIdx.x;
    float acc = b0[j];
    #pragma unroll
    for (int k = 0; k < 16; ++k)
        acc = fmaf(se[r * 16 + k], W0[k * 64 + j], acc);
    seqT[r * 64 + j] = acc;
}

// kmerTable[r][j] = sum_k kmer_embed[r][k]*W0[16+k][j]   (10648 x 64)
// 8 rows per 64-thread block; embed values are wave-uniform -> s_loads.
__global__ __launch_bounds__(64) void kmer_table_kernel(
    const float* __restrict__ emb, const float* __restrict__ W0,
    float* __restrict__ kt) {
    int j  = threadIdx.x;
    int r0 = blockIdx.x * 8;
    float acc[8] = {0.f, 0.f, 0.f, 0.f, 0.f, 0.f, 0.f, 0.f};
    #pragma unroll 8
    for (int k = 0; k < 256; ++k) {
        float w = W0[(16 + k) * 64 + j];   // coalesced per-lane
        #pragma unroll
        for (int r = 0; r < 8; ++r)
            acc[r] = fmaf(emb[(r0 + r) * 256 + k], w, acc[r]);  // emb uniform -> SGPR
    }
    #pragma unroll
    for (int r = 0; r < 8; ++r)
        kt[(r0 + r) * 64 + j] = acc[r];
}

// ---------- Fused MLP kernel ----------
// One thread per (l,b) position. h0 = seqT[seq] + kmerT[kmer] + pssm@W0p;
// two shared ReLU layers; srf head. Output layout srf_t[(l*9+m)*256 + b]
// (m-major, batch-contiguous) so both store here and load in extend are coalesced.
__global__ __launch_bounds__(256, 2) void mlp_kernel(
    const int* __restrict__ seq, const int* __restrict__ kmer,
    const float* __restrict__ pssm,
    const float* __restrict__ seqT, const float* __restrict__ kmerT,
    const float* __restrict__ W0, const float* __restrict__ We,
    const float* __restrict__ be, const float* __restrict__ W1,
    const float* __restrict__ b1, float* __restrict__ srf_t) {
    int idx = blockIdx.x * 256 + threadIdx.x;   // l*256 + b
    int b   = idx & 255;
    int l   = idx >> 8;

    int s  = seq[idx];
    int km = kmer[idx];

    const float4* st = (const float4*)(seqT + (s << 6));
    const float4* kt = (const float4*)(kmerT + (km << 6));

    float h[64];
    #pragma unroll
    for (int q = 0; q < 16; ++q) {
        float4 A = st[q];
        float4 C = kt[q];
        h[4 * q + 0] = A.x + C.x;
        h[4 * q + 1] = A.y + C.y;
        h[4 * q + 2] = A.z + C.z;
        h[4 * q + 3] = A.w + C.w;
    }

    // pssm contribution: 21 x 64 GEMV, weights wave-uniform
    float p[21];
    #pragma unroll
    for (int c = 0; c < 21; ++c) p[c] = pssm[idx * 21 + c];
    #pragma unroll
    for (int c = 0; c < 21; ++c) {
        float pc = p[c];
        #pragma unroll
        for (int j = 0; j < 64; ++j)
            h[j] = fmaf(pc, W0[(272 + c) * 64 + j], h[j]);
    }

    // two ReLU layers sharing We/be
    for (int layer = 0; layer < 2; ++layer) {
        float hn[64];
        #pragma unroll
        for (int j = 0; j < 64; ++j) hn[j] = be[j];
        #pragma unroll
        for (int k = 0; k < 64; ++k) {
            float hk = h[k];
            #pragma unroll
            for (int j = 0; j < 64; ++j)
                hn[j] = fmaf(hk, We[k * 64 + j], hn[j]);
        }
        #pragma unroll
        for (int j = 0; j < 64; ++j) h[j] = fmaxf(hn[j], 0.0f);
    }

    // srf head: 64 -> 9
    float o[9];
    #pragma unroll
    for (int m = 0; m < 9; ++m) o[m] = b1[m];
    #pragma unroll
    for (int j = 0; j < 64; ++j) {
        float hj = h[j];
        #pragma unroll
        for (int m = 0; m < 9; ++m)
            o[m] = fmaf(hj, W1[j * 9 + m], o[m]);
    }

    #pragma unroll
    for (int m = 0; m < 9; ++m)
        srf_t[(l * 9 + m) * 256 + b] = o[m];
}

// ---------- pNeRF phase 1: per-fragment extension ----------
// chain (frag, b): 96 sequential NeRF steps; ct for step j=3*ll+s3 is
// srf[l = frag*32+ll, b, 3*s3 .. 3*s3+2]. fragbuf layout [(row*3+c)*256 + b].
__global__ __launch_bounds__(64) void extend_kernel(
    const float* __restrict__ srf_t, float* __restrict__ fragbuf) {
    int frag = blockIdx.x >> 2;
    int bb   = ((blockIdx.x & 3) << 6) + threadIdx.x;

    float3 A  = make_float3(-0.70710678118654752f, 1.22474487139158905f, 0.f);
    float3 Bv = make_float3(-1.41421356237309505f, 0.f, 0.f);
    float3 C  = make_float3(0.f, 0.f, 0.f);

    float ct[9];
    #pragma unroll
    for (int m = 0; m < 9; ++m)
        ct[m] = srf_t[((frag * 32) * 9 + m) * 256 + bb];

    for (int ll = 0; ll < 32; ++ll) {
        float nct[9];
        if (ll < 31) {   // uniform branch; prefetch next residue's 9 floats
            #pragma unroll
            for (int m = 0; m < 9; ++m)
                nct[m] = srf_t[((frag * 32 + ll + 1) * 9 + m) * 256 + bb];
        }
        #pragma unroll
        for (int s3 = 0; s3 < 3; ++s3) {
            float3 bc = f3norm(f3sub(C, Bv));
            float3 n  = f3norm(f3cross(f3sub(Bv, A), bc));
            float3 m3 = f3cross(n, bc);
            float tx = ct[3 * s3 + 0], ty = ct[3 * s3 + 1], tz = ct[3 * s3 + 2];
            float3 d = make_float3(
                C.x + bc.x * tx + m3.x * ty + n.x * tz,
                C.y + bc.y * tx + m3.y * ty + n.y * tz,
                C.z + bc.z * tx + m3.z * ty + n.z * tz);
            int row = frag * 96 + ll * 3 + s3;
            fragbuf[(row * 3 + 0) * 256 + bb] = d.x;
            fragbuf[(row * 3 + 1) * 256 + bb] = d.y;
            fragbuf[(row * 3 + 2) * 256 + bb] = d.z;
            A = Bv; Bv = C; C = d;
        }
        #pragma unroll
        for (int m = 0; m < 9; ++m) ct[m] = nct[m];
    }
}

// ---------- pNeRF phase 2a: sequential carry chain over fragments ----------
// One thread per batch column. Records each fragment's frame (R columns bc,m,n
// and origin C) into frames[(frag*12+q)*256 + b], then advances the carry with
// that fragment's last three points.
__global__ __launch_bounds__(256) void carry_kernel(
    const float* __restrict__ fragbuf, float* __restrict__ frames) {
    int bb = threadIdx.x;
    float3 A  = make_float3(-0.70710678118654752f, 1.22474487139158905f, 0.f);
    float3 Bv = make_float3(-1.41421356237309505f, 0.f, 0.f);
    float3 C  = make_float3(0.f, 0.f, 0.f);

    float fr[9];
    #pragma unroll
    for (int t = 0; t < 3; ++t)
        #pragma unroll
        for (int c = 0; c < 3; ++c)
            fr[t * 3 + c] = fragbuf[(((93 + t)) * 3 + c) * 256 + bb];

    for (int frag = 0; frag < 32; ++frag) {
        float nfr[9];
        if (frag < 31) {
            #pragma unroll
            for (int t = 0; t < 3; ++t)
                #pragma unroll
                for (int c = 0; c < 3; ++c)
                    nfr[t * 3 + c] =
                        fragbuf[(((frag + 1) * 96 + 93 + t) * 3 + c) * 256 + bb];
        }
        float3 bc = f3norm(f3sub(C, Bv));
        float3 n  = f3norm(f3cross(f3sub(Bv, A), bc));
        float3 m3 = f3cross(n, bc);

        frames[(frag * 12 + 0)  * 256 + bb] = bc.x;
        frames[(frag * 12 + 1)  * 256 + bb] = bc.y;
        frames[(frag * 12 + 2)  * 256 + bb] = bc.z;
        frames[(frag * 12 + 3)  * 256 + bb] = m3.x;
        frames[(frag * 12 + 4)  * 256 + bb] = m3.y;
        frames[(frag * 12 + 5)  * 256 + bb] = m3.z;
        frames[(frag * 12 + 6)  * 256 + bb] = n.x;
        frames[(frag * 12 + 7)  * 256 + bb] = n.y;
        frames[(frag * 12 + 8)  * 256 + bb] = n.z;
        frames[(frag * 12 + 9)  * 256 + bb] = C.x;
        frames[(frag * 12 + 10) * 256 + bb] = C.y;
        frames[(frag * 12 + 11) * 256 + bb] = C.z;

        float3 y[3];
        #pragma unroll
        for (int t = 0; t < 3; ++t) {
            float fx = fr[t * 3 + 0], fy = fr[t * 3 + 1], fz = fr[t * 3 + 2];
            y[t] = make_float3(
                C.x + bc.x * fx + m3.x * fy + n.x * fz,
                C.y + bc.y * fx + m3.y * fy + n.y * fz,
                C.z + bc.z * fx + m3.z * fy + n.z * fz);
        }
        A = y[0]; Bv = y[1]; C = y[2];
        #pragma unroll
        for (int m = 0; m < 9; ++m) fr[m] = nfr[m];
    }
}

// ---------- pNeRF phase 2b: parallel application of fragment frames ----------
__global__ __launch_bounds__(256) void apply_kernel(
    const float* __restrict__ fragbuf, const float* __restrict__ frames,
    float* __restrict__ out) {
    int bb   = threadIdx.x;
    int row  = blockIdx.x;       // 0..3071
    int frag = row / 96;

    float fx = fragbuf[(row * 3 + 0) * 256 + bb];
    float fy = fragbuf[(row * 3 + 1) * 256 + bb];
    float fz = fragbuf[(row * 3 + 2) * 256 + bb];

    float bcx = frames[(frag * 12 + 0)  * 256 + bb];
    float bcy = frames[(frag * 12 + 1)  * 256 + bb];
    float bcz = frames[(frag * 12 + 2)  * 256 + bb];
    float mx  = frames[(frag * 12 + 3)  * 256 + bb];
    float my  = frames[(frag * 12 + 4)  * 256 + bb];
    float mz  = frames[(frag * 12 + 5)  * 256 + bb];
    float nx  = frames[(frag * 12 + 6)  * 256 + bb];
    float ny  = frames[(frag * 12 + 7)  * 256 + bb];
    float nz  = frames[(frag * 12 + 8)  * 256 + bb];
    float cx  = frames[(frag * 12 + 9)  * 256 + bb];
    float cy  = frames[(frag * 12 + 10) * 256 + bb];
    float cz  = frames[(frag * 12 + 11) * 256 + bb];

    float ox = cx + bcx * fx + mx * fy + nx * fz;
    float oy = cy + bcy * fx + my * fy + ny * fz;
    float oz = cz + bcz * fx + mz * fy + nz * fz;

    out[(row * 256 + bb) * 3 + 0] = ox;
    out[(row * 256 + bb) * 3 + 1] = oy;
    out[(row * 256 + bb) * 3 + 2] = oz;
}

// ---------- host launch ----------
extern "C" void kernel_launch(void* const* d_in, const int* in_sizes, int n_in,
                              void* d_out, int out_size, void* d_ws, size_t ws_size,
                              hipStream_t stream) {
    const int*   seq        = (const int*)d_in[0];
    const int*   kmer       = (const int*)d_in[1];
    const float* pssm       = (const float*)d_in[2];
    // d_in[3] = length (unused by reference)
    const float* seq_embed  = (const float*)d_in[4];
    const float* kmer_embed = (const float*)d_in[5];
    const float* W0         = (const float*)d_in[6];
    const float* b0         = (const float*)d_in[7];
    const float* We         = (const float*)d_in[8];
    const float* be         = (const float*)d_in[9];
    const float* W1         = (const float*)d_in[10];
    const float* b1         = (const float*)d_in[11];

    float* ws      = (float*)d_ws;
    float* kmerT   = ws;                       // 10648*64 = 681472
    float* seqT    = kmerT + 681472;           // 20*64    = 1280
    float* srf_t   = seqT + 1280;              // 1024*9*256 = 2359296
    float* fragbuf = srf_t + 2359296;          // 3072*3*256 = 2359296
    float* frames  = fragbuf + 2359296;        // 32*12*256  = 98304
    float* out     = (float*)d_out;

    hipLaunchKernelGGL(seq_table_kernel, dim3(20), dim3(64), 0, stream,
                       seq_embed, W0, b0, seqT);
    hipLaunchKernelGGL(kmer_table_kernel, dim3(NKMER / 8), dim3(64), 0, stream,
                       kmer_embed, W0, kmerT);
    hipLaunchKernelGGL(mlp_kernel, dim3(1024), dim3(256), 0, stream,
                       seq, kmer, pssm, seqT, kmerT, W0, We, be, W1, b1, srf_t);
    hipLaunchKernelGGL(extend_kernel, dim3(128), dim3(64), 0, stream,
                       srf_t, fragbuf);
    hipLaunchKernelGGL(carry_kernel, dim3(1), dim3(256), 0, stream,
                       fragbuf, frames);
    hipLaunchKernelGGL(apply_kernel, dim3(3072), dim3(256), 0, stream,
                       fragbuf, frames, out);
}

// Round 2
// 355.527 us; speedup vs baseline: 1.2042x; 1.2042x over previous
//
#include <hip/hip_runtime.h>
#include <math.h>

// Problem constants (match reference)
#define LQ     1024          // sequence length
#define BQ     256           // batch
#define NFRAG  32            // sqrt(LQ)
#define NKMER  10648         // 22^3
#define HID    64

// ---------- fast inverse-norm ----------
__device__ __forceinline__ float inv_norm3(float x, float y, float z) {
    float d = fmaf(x, x, fmaf(y, y, z * z));
#if __has_builtin(__builtin_amdgcn_rsqf)
    return __builtin_amdgcn_rsqf(fmaxf(d, 1e-24f));   // v_rsq_f32, ~1 ulp
#else
    return rsqrtf(fmaxf(d, 1e-24f));
#endif
}

__device__ __forceinline__ float3 f3sub(float3 a, float3 b) {
    return make_float3(a.x - b.x, a.y - b.y, a.z - b.z);
}
__device__ __forceinline__ float3 f3cross(float3 a, float3 b) {
    return make_float3(a.y * b.z - a.z * b.y,
                       a.z * b.x - a.x * b.z,
                       a.x * b.y - a.y * b.x);
}
__device__ __forceinline__ float3 f3norm(float3 v) {
    float inv = inv_norm3(v.x, v.y, v.z);
    return make_float3(v.x * inv, v.y * inv, v.z * inv);
}

// ---------- Table precompute kernels ----------
// seqTable[r][j] = sum_k seq_embed[r][k]*W0[k][j] + b0[j]   (20 x 64)
__global__ __launch_bounds__(64) void seq_table_kernel(
    const float* __restrict__ se, const float* __restrict__ W0,
    const float* __restrict__ b0, float* __restrict__ seqT) {
    int j = threadIdx.x;
    int r = blockIdx.x;
    float acc = b0[j];
    #pragma unroll
    for (int k = 0; k < 16; ++k)
        acc = fmaf(se[r * 16 + k], W0[k * 64 + j], acc);
    seqT[r * 64 + j] = acc;
}

// kmerTable[r][j] = sum_k kmer_embed[r][k]*W0[16+k][j]   (10648 x 64)
__global__ __launch_bounds__(64) void kmer_table_kernel(
    const float* __restrict__ emb, const float* __restrict__ W0,
    float* __restrict__ kt) {
    int j  = threadIdx.x;
    int r0 = blockIdx.x * 8;
    float acc[8] = {0.f, 0.f, 0.f, 0.f, 0.f, 0.f, 0.f, 0.f};
    #pragma unroll 8
    for (int k = 0; k < 256; ++k) {
        float w = W0[(16 + k) * 64 + j];   // coalesced per-lane
        #pragma unroll
        for (int r = 0; r < 8; ++r)
            acc[r] = fmaf(emb[(r0 + r) * 256 + k], w, acc[r]);  // emb uniform -> SGPR
    }
    #pragma unroll
    for (int r = 0; r < 8; ++r)
        kt[(r0 + r) * 64 + j] = acc[r];
}

// ---------- Fused MLP kernel, wave-cooperative half-split ----------
// Block = 256 threads = 4 waves = 2 position-groups of 64.
// Within a group, wave pair (half=0 / half=1) each computes 32 of the 64
// hidden outputs; layer boundaries exchange halves through LDS.
// Register budget by construction: h[64] + hn[32] + misc ~= 110 VGPR, no
// dynamic VGPR-array indexing anywhere (dynamic index -> scratch = round-1 bug).
// `half` is forced uniform via readfirstlane so We/W1/be/W0 accesses are
// provably wave-uniform -> s_load (scalar cache), keeping VALU pure FMA.
__global__ __launch_bounds__(256, 3) void mlp_kernel(
    const int* __restrict__ seq, const int* __restrict__ kmer,
    const float* __restrict__ pssm,
    const float* __restrict__ seqT, const float* __restrict__ kmerT,
    const float* __restrict__ W0, const float* __restrict__ We,
    const float* __restrict__ be, const float* __restrict__ W1,
    const float* __restrict__ b1, float* __restrict__ srf_t) {
    const int tid   = threadIdx.x;
    const int lane  = tid & 63;
    const int group = __builtin_amdgcn_readfirstlane((tid >> 7) & 1); // 0,1
    const int half  = __builtin_amdgcn_readfirstlane((tid >> 6) & 1); // 0,1

    const int idx = blockIdx.x * 128 + group * 64 + lane;  // position
    const int b   = idx & 255;
    const int l   = idx >> 8;

    __shared__ float ex[2][64][64];   // [group][row][lane], bank-conflict-free

    const int s  = seq[idx];
    const int km = kmer[idx];

    // ---- layer 0: my half of h0 = seqT[s] + kmerT[km] + pssm @ W0p ----
    float hn[32];
    {
        const float4* st = (const float4*)(seqT + (s << 6) + (half << 5));
        const float4* kt = (const float4*)(kmerT + (km << 6) + (half << 5));
        #pragma unroll
        for (int q = 0; q < 8; ++q) {
            float4 A = st[q];
            float4 C = kt[q];
            hn[4 * q + 0] = A.x + C.x;
            hn[4 * q + 1] = A.y + C.y;
            hn[4 * q + 2] = A.z + C.z;
            hn[4 * q + 3] = A.w + C.w;
        }
        float p[21];
        #pragma unroll
        for (int c = 0; c < 21; ++c) p[c] = pssm[idx * 21 + c];
        const float* W0p = W0 + 272 * 64 + (half << 5);   // uniform base
        #pragma unroll
        for (int c = 0; c < 21; ++c) {
            float pc = p[c];
            #pragma unroll
            for (int i = 0; i < 32; ++i)
                hn[i] = fmaf(pc, W0p[c * 64 + i], hn[i]);
        }
    }

    // ---- two shared ReLU layers ----
    const float* Weh = We + (half << 5);   // uniform base for my 32 columns
    const float* beh = be + (half << 5);
    #pragma unroll 1
    for (int layer = 0; layer < 2; ++layer) {
        __syncthreads();                        // prior reads done before overwrite
        #pragma unroll
        for (int i = 0; i < 32; ++i)
            ex[group][(half << 5) + i][lane] = hn[i];
        __syncthreads();
        float h[64];
        #pragma unroll
        for (int r = 0; r < 64; ++r)
            h[r] = ex[group][r][lane];

        #pragma unroll
        for (int i = 0; i < 32; ++i) hn[i] = beh[i];
        #pragma unroll
        for (int k = 0; k < 64; ++k) {
            float hk = h[k];
            #pragma unroll
            for (int i = 0; i < 32; ++i)
                hn[i] = fmaf(hk, Weh[k * 64 + i], hn[i]);
        }
        #pragma unroll
        for (int i = 0; i < 32; ++i) hn[i] = fmaxf(hn[i], 0.0f);
    }

    // ---- srf head: partial over my 32 j's, reduce across wave pair ----
    float o[9];
    #pragma unroll
    for (int m = 0; m < 9; ++m) o[m] = (half == 0) ? b1[m] : 0.0f;
    const float* W1h = W1 + (half << 5) * 9;   // uniform base
    #pragma unroll
    for (int i = 0; i < 32; ++i) {
        float hi = hn[i];
        #pragma unroll
        for (int m = 0; m < 9; ++m)
            o[m] = fmaf(hi, W1h[i * 9 + m], o[m]);
    }
    __syncthreads();
    if (half == 1) {
        #pragma unroll
        for (int m = 0; m < 9; ++m) ex[group][m][lane] = o[m];
    }
    __syncthreads();
    if (half == 0) {
        #pragma unroll
        for (int m = 0; m < 9; ++m) {
            float v = o[m] + ex[group][m][lane];
            srf_t[(l * 9 + m) * 256 + b] = v;   // coalesced 64-lane store
        }
    }
}

// ---------- pNeRF phase 1: per-fragment extension ----------
__global__ __launch_bounds__(64) void extend_kernel(
    const float* __restrict__ srf_t, float* __restrict__ fragbuf) {
    int frag = blockIdx.x >> 2;
    int bb   = ((blockIdx.x & 3) << 6) + threadIdx.x;

    float3 A  = make_float3(-0.70710678118654752f, 1.22474487139158905f, 0.f);
    float3 Bv = make_float3(-1.41421356237309505f, 0.f, 0.f);
    float3 C  = make_float3(0.f, 0.f, 0.f);

    float ct[9];
    #pragma unroll
    for (int m = 0; m < 9; ++m)
        ct[m] = srf_t[((frag * 32) * 9 + m) * 256 + bb];

    for (int ll = 0; ll < 32; ++ll) {
        float nct[9];
        if (ll < 31) {   // uniform branch; prefetch next residue's 9 floats
            #pragma unroll
            for (int m = 0; m < 9; ++m)
                nct[m] = srf_t[((frag * 32 + ll + 1) * 9 + m) * 256 + bb];
        }
        #pragma unroll
        for (int s3 = 0; s3 < 3; ++s3) {
            float3 bc = f3norm(f3sub(C, Bv));
            float3 n  = f3norm(f3cross(f3sub(Bv, A), bc));
            float3 m3 = f3cross(n, bc);
            float tx = ct[3 * s3 + 0], ty = ct[3 * s3 + 1], tz = ct[3 * s3 + 2];
            float3 d = make_float3(
                C.x + bc.x * tx + m3.x * ty + n.x * tz,
                C.y + bc.y * tx + m3.y * ty + n.y * tz,
                C.z + bc.z * tx + m3.z * ty + n.z * tz);
            int row = frag * 96 + ll * 3 + s3;
            fragbuf[(row * 3 + 0) * 256 + bb] = d.x;
            fragbuf[(row * 3 + 1) * 256 + bb] = d.y;
            fragbuf[(row * 3 + 2) * 256 + bb] = d.z;
            A = Bv; Bv = C; C = d;
        }
        #pragma unroll
        for (int m = 0; m < 9; ++m) ct[m] = nct[m];
    }
}

// ---------- pNeRF phase 2a: sequential carry chain over fragments ----------
__global__ __launch_bounds__(256) void carry_kernel(
    const float* __restrict__ fragbuf, float* __restrict__ frames) {
    int bb = threadIdx.x;
    float3 A  = make_float3(-0.70710678118654752f, 1.22474487139158905f, 0.f);
    float3 Bv = make_float3(-1.41421356237309505f, 0.f, 0.f);
    float3 C  = make_float3(0.f, 0.f, 0.f);

    float fr[9];
    #pragma unroll
    for (int t = 0; t < 3; ++t)
        #pragma unroll
        for (int c = 0; c < 3; ++c)
            fr[t * 3 + c] = fragbuf[(((93 + t)) * 3 + c) * 256 + bb];

    for (int frag = 0; frag < 32; ++frag) {
        float nfr[9];
        if (frag < 31) {
            #pragma unroll
            for (int t = 0; t < 3; ++t)
                #pragma unroll
                for (int c = 0; c < 3; ++c)
                    nfr[t * 3 + c] =
                        fragbuf[(((frag + 1) * 96 + 93 + t) * 3 + c) * 256 + bb];
        }
        float3 bc = f3norm(f3sub(C, Bv));
        float3 n  = f3norm(f3cross(f3sub(Bv, A), bc));
        float3 m3 = f3cross(n, bc);

        frames[(frag * 12 + 0)  * 256 + bb] = bc.x;
        frames[(frag * 12 + 1)  * 256 + bb] = bc.y;
        frames[(frag * 12 + 2)  * 256 + bb] = bc.z;
        frames[(frag * 12 + 3)  * 256 + bb] = m3.x;
        frames[(frag * 12 + 4)  * 256 + bb] = m3.y;
        frames[(frag * 12 + 5)  * 256 + bb] = m3.z;
        frames[(frag * 12 + 6)  * 256 + bb] = n.x;
        frames[(frag * 12 + 7)  * 256 + bb] = n.y;
        frames[(frag * 12 + 8)  * 256 + bb] = n.z;
        frames[(frag * 12 + 9)  * 256 + bb] = C.x;
        frames[(frag * 12 + 10) * 256 + bb] = C.y;
        frames[(frag * 12 + 11) * 256 + bb] = C.z;

        float3 y[3];
        #pragma unroll
        for (int t = 0; t < 3; ++t) {
            float fx = fr[t * 3 + 0], fy = fr[t * 3 + 1], fz = fr[t * 3 + 2];
            y[t] = make_float3(
                C.x + bc.x * fx + m3.x * fy + n.x * fz,
                C.y + bc.y * fx + m3.y * fy + n.y * fz,
                C.z + bc.z * fx + m3.z * fy + n.z * fz);
        }
        A = y[0]; Bv = y[1]; C = y[2];
        #pragma unroll
        for (int m = 0; m < 9; ++m) fr[m] = nfr[m];
    }
}

// ---------- pNeRF phase 2b: parallel application of fragment frames ----------
__global__ __launch_bounds__(256) void apply_kernel(
    const float* __restrict__ fragbuf, const float* __restrict__ frames,
    float* __restrict__ out) {
    int bb   = threadIdx.x;
    int row  = blockIdx.x;       // 0..3071
    int frag = row / 96;

    float fx = fragbuf[(row * 3 + 0) * 256 + bb];
    float fy = fragbuf[(row * 3 + 1) * 256 + bb];
    float fz = fragbuf[(row * 3 + 2) * 256 + bb];

    float bcx = frames[(frag * 12 + 0)  * 256 + bb];
    float bcy = frames[(frag * 12 + 1)  * 256 + bb];
    float bcz = frames[(frag * 12 + 2)  * 256 + bb];
    float mx  = frames[(frag * 12 + 3)  * 256 + bb];
    float my  = frames[(frag * 12 + 4)  * 256 + bb];
    float mz  = frames[(frag * 12 + 5)  * 256 + bb];
    float nx  = frames[(frag * 12 + 6)  * 256 + bb];
    float ny  = frames[(frag * 12 + 7)  * 256 + bb];
    float nz  = frames[(frag * 12 + 8)  * 256 + bb];
    float cx  = frames[(frag * 12 + 9)  * 256 + bb];
    float cy  = frames[(frag * 12 + 10) * 256 + bb];
    float cz  = frames[(frag * 12 + 11) * 256 + bb];

    float ox = cx + bcx * fx + mx * fy + nx * fz;
    float oy = cy + bcy * fx + my * fy + ny * fz;
    float oz = cz + bcz * fx + mz * fy + nz * fz;

    out[(row * 256 + bb) * 3 + 0] = ox;
    out[(row * 256 + bb) * 3 + 1] = oy;
    out[(row * 256 + bb) * 3 + 2] = oz;
}

// ---------- host launch ----------
extern "C" void kernel_launch(void* const* d_in, const int* in_sizes, int n_in,
                              void* d_out, int out_size, void* d_ws, size_t ws_size,
                              hipStream_t stream) {
    const int*   seq        = (const int*)d_in[0];
    const int*   kmer       = (const int*)d_in[1];
    const float* pssm       = (const float*)d_in[2];
    // d_in[3] = length (unused by reference)
    const float* seq_embed  = (const float*)d_in[4];
    const float* kmer_embed = (const float*)d_in[5];
    const float* W0         = (const float*)d_in[6];
    const float* b0         = (const float*)d_in[7];
    const float* We         = (const float*)d_in[8];
    const float* be         = (const float*)d_in[9];
    const float* W1         = (const float*)d_in[10];
    const float* b1         = (const float*)d_in[11];

    float* ws      = (float*)d_ws;
    float* kmerT   = ws;                       // 10648*64 = 681472
    float* seqT    = kmerT + 681472;           // 20*64    = 1280
    float* srf_t   = seqT + 1280;              // 1024*9*256 = 2359296
    float* fragbuf = srf_t + 2359296;          // 3072*3*256 = 2359296
    float* frames  = fragbuf + 2359296;        // 32*12*256  = 98304
    float* out     = (float*)d_out;

    hipLaunchKernelGGL(seq_table_kernel, dim3(20), dim3(64), 0, stream,
                       seq_embed, W0, b0, seqT);
    hipLaunchKernelGGL(kmer_table_kernel, dim3(NKMER / 8), dim3(64), 0, stream,
                       kmer_embed, W0, kmerT);
    hipLaunchKernelGGL(mlp_kernel, dim3(2048), dim3(256), 0, stream,
                       seq, kmer, pssm, seqT, kmerT, W0, We, be, W1, b1, srf_t);
    hipLaunchKernelGGL(extend_kernel, dim3(128), dim3(64), 0, stream,
                       srf_t, fragbuf);
    hipLaunchKernelGGL(carry_kernel, dim3(1), dim3(256), 0, stream,
                       fragbuf, frames);
    hipLaunchKernelGGL(apply_kernel, dim3(3072), dim3(256), 0, stream,
                       fragbuf, frames, out);
}

// Round 4
// 218.097 us; speedup vs baseline: 1.9630x; 1.6301x over previous
//
#include <hip/hip_runtime.h>
#include <math.h>

#define HPAD 72      // LDS row stride (shorts) for 64-wide rows; 144 B, 16B-aligned
#define PPAD 40      // LDS row stride for 32-wide pssm rows

typedef short bf16x8 __attribute__((ext_vector_type(8)));
typedef float f32x4  __attribute__((ext_vector_type(4)));

// round-to-nearest-even float -> bf16 bits
__device__ __forceinline__ unsigned short f2bf(float x) {
    unsigned int u = __float_as_uint(x);
    return (unsigned short)((u + 0x7FFFu + ((u >> 16) & 1u)) >> 16);
}
__device__ __forceinline__ float bf2f(unsigned short h) {
    return __uint_as_float(((unsigned int)h) << 16);
}
// split x into hi+lo bf16 pair (hi = RNE(x), lo = RNE(x - hi); subtraction exact)
__device__ __forceinline__ void split2(float x, unsigned short& h, unsigned short& l) {
    h = f2bf(x);
    l = f2bf(x - bf2f(h));
}

__device__ __forceinline__ float inv_norm3(float x, float y, float z) {
    float d = fmaf(x, x, fmaf(y, y, z * z));
    return rsqrtf(fmaxf(d, 1e-24f));
}
__device__ __forceinline__ float3 f3sub(float3 a, float3 b) {
    return make_float3(a.x - b.x, a.y - b.y, a.z - b.z);
}
__device__ __forceinline__ float3 f3cross(float3 a, float3 b) {
    return make_float3(a.y * b.z - a.z * b.y,
                       a.z * b.x - a.x * b.z,
                       a.x * b.y - a.y * b.x);
}
// NeRF frame with parallel normalizations (n from unnormalized w: same direction)
__device__ __forceinline__ void nerf_frame(const float3& A, const float3& Bv,
                                           const float3& C, float3& bc,
                                           float3& n, float3& m3) {
    float3 w  = f3sub(C, Bv);
    float3 v  = f3sub(Bv, A);
    float3 cr = f3cross(v, w);
    float iw = inv_norm3(w.x, w.y, w.z);
    float ic = inv_norm3(cr.x, cr.y, cr.z);
    bc = make_float3(w.x * iw, w.y * iw, w.z * iw);
    n  = make_float3(cr.x * ic, cr.y * ic, cr.z * ic);
    m3 = f3cross(n, bc);
}
__device__ __forceinline__ float3 nerf_place(const float3& C, const float3& bc,
                                             const float3& m3, const float3& n,
                                             float tx, float ty, float tz) {
    return make_float3(
        fmaf(m3.x, ty, fmaf(bc.x, tx, fmaf(n.x, tz, C.x))),
        fmaf(m3.y, ty, fmaf(bc.y, tx, fmaf(n.y, tz, C.y))),
        fmaf(m3.z, ty, fmaf(bc.z, tx, fmaf(n.z, tz, C.z))));
}

// ---------- Table precompute ----------
// seqT[r][j] = seq_embed[r]@W0[0:16] + b0[j] + 0.5*sum_c W0p[c][j]
// (0.5 term compensates centering pssm by -0.5 before split quantization)
__global__ __launch_bounds__(64) void seq_table_kernel(
    const float* __restrict__ se, const float* __restrict__ W0,
    const float* __restrict__ b0, float* __restrict__ seqT) {
    int j = threadIdx.x;
    int r = blockIdx.x;
    float acc = b0[j];
    #pragma unroll
    for (int k = 0; k < 16; ++k)
        acc = fmaf(se[r * 16 + k], W0[k * 64 + j], acc);
    float cs = 0.f;
    #pragma unroll
    for (int c = 0; c < 21; ++c) cs += W0[(272 + c) * 64 + j];
    seqT[r * 64 + j] = acc + 0.5f * cs;
}

// kmerTable: 10648 x 64, fp32 exact. 256-thread blocks, 11 rows/wave, 44/block.
// 242 * 44 == 10648 exactly.
__global__ __launch_bounds__(256) void kmer_table_kernel(
    const float* __restrict__ emb, const float* __restrict__ W0,
    float* __restrict__ kt) {
    int j  = threadIdx.x & 63;
    int wv = threadIdx.x >> 6;
    int r0 = blockIdx.x * 44 + wv * 11;
    float acc[11] = {0.f,0.f,0.f,0.f,0.f,0.f,0.f,0.f,0.f,0.f,0.f};
    #pragma unroll 8
    for (int k = 0; k < 256; ++k) {
        float w = W0[(16 + k) * 64 + j];        // per-lane coalesced
        #pragma unroll
        for (int r = 0; r < 11; ++r)
            acc[r] = fmaf(emb[(r0 + r) * 256 + k], w, acc[r]);  // wave-uniform -> s_load
    }
    #pragma unroll
    for (int r = 0; r < 11; ++r)
        kt[(r0 + r) * 64 + j] = acc[r];
}

// ---------- split-bf16 MFMA MLP ----------
// Block = 256 thr = 4 waves, M = 64 positions. Wave wv owns N-strip [16wv,16wv+16)
// for layers 0..2, M-tile wv for the head. Every operand is hi+lo bf16; each
// logical matmul = Ah*Bh + Al*Bh + Ah*Bl with fp32 accum (~2^-18 rel error).
// Exact fp32 path: seqT/kmerT gathers enter the MFMA C operand directly.
__global__ __launch_bounds__(256, 3) void mlp_kernel(
    const int* __restrict__ seq, const int* __restrict__ kmer,
    const float* __restrict__ pssm,
    const float* __restrict__ seqT, const float* __restrict__ kmerT,
    const float* __restrict__ W0, const float* __restrict__ We,
    const float* __restrict__ be, const float* __restrict__ W1,
    const float* __restrict__ b1, float* __restrict__ srf_t) {

    __shared__ __align__(16) unsigned short Hah[64][HPAD];   // H hi [m][k]
    __shared__ __align__(16) unsigned short Hal[64][HPAD];   // H lo [m][k]
    // overlay region: pssm pair (layer 0 only) then Hb pair (layers 1+)
    __shared__ __align__(16) unsigned short ovl[2][64][HPAD];
    __shared__ int sidx[64];
    __shared__ int kidx[64];

    unsigned short (*Ph)[PPAD] = (unsigned short(*)[PPAD])(&ovl[0][0][0]);
    unsigned short (*Pl)[PPAD] = (unsigned short(*)[PPAD])(&ovl[0][0][0] + 2560);
    unsigned short (*Hbh)[HPAD] = ovl[0];
    unsigned short (*Hbl)[HPAD] = ovl[1];

    const int tid  = threadIdx.x;
    const int lane = tid & 63;
    const int wv   = __builtin_amdgcn_readfirstlane(tid >> 6);  // 0..3
    const int q    = lane >> 4;
    const int c16  = lane & 15;
    const int m0   = blockIdx.x * 64;
    const int n    = wv * 16 + c16;   // my output column for layers 0..2

    // ---- stage indices + centered pssm (split) into LDS ----
    if (tid < 64) {
        sidx[tid] = seq[m0 + tid];
        kidx[tid] = kmer[m0 + tid];
    }
    for (int i = tid; i < 64 * 21; i += 256) {
        float v = pssm[m0 * 21 + i] - 0.5f;
        unsigned short h, l; split2(v, h, l);
        Ph[i / 21][i % 21] = h;
        Pl[i / 21][i % 21] = l;
    }
    for (int i = tid; i < 64 * 11; i += 256) {   // zero K-pad cols 21..31
        Ph[i / 11][21 + (i % 11)] = 0;
        Pl[i / 11][21 + (i % 11)] = 0;
    }

    // ---- per-lane weight fragments in registers (L2-hot gathers) ----
    bf16x8 WeH[2], WeL[2], W1H[2], W1L[2], W0H, W0L;
    #pragma unroll
    for (int kk = 0; kk < 2; ++kk)
        #pragma unroll
        for (int j = 0; j < 8; ++j) {
            float w = We[(kk * 32 + q * 8 + j) * 64 + n];
            unsigned short h, l; split2(w, h, l);
            WeH[kk][j] = (short)h; WeL[kk][j] = (short)l;
        }
    #pragma unroll
    for (int j = 0; j < 8; ++j) {
        int k = q * 8 + j;
        float w = (k < 21) ? W0[(272 + k) * 64 + n] : 0.f;
        unsigned short h, l; split2(w, h, l);
        W0H[j] = (short)h; W0L[j] = (short)l;
    }
    #pragma unroll
    for (int kk = 0; kk < 2; ++kk)
        #pragma unroll
        for (int j = 0; j < 8; ++j) {
            int k = kk * 32 + q * 8 + j;
            float w = (c16 < 9) ? W1[k * 9 + c16] : 0.f;
            unsigned short h, l; split2(w, h, l);
            W1H[kk][j] = (short)h; W1L[kk][j] = (short)l;
        }
    const float be_n = be[n];
    const float b1h  = (c16 < 9) ? b1[c16] : 0.f;
    __syncthreads();

    // ---- layer 0: C = exact fp32 gathers; A = pssm pair, B = W0p pair ----
    f32x4 acc[4];
    #pragma unroll
    for (int t = 0; t < 4; ++t) {
        #pragma unroll
        for (int r = 0; r < 4; ++r) {
            int m = t * 16 + q * 4 + r;          // C/D: row = quad*4+reg
            acc[t][r] = seqT[sidx[m] * 64 + n] + kmerT[kidx[m] * 64 + n];
        }
    }
    #pragma unroll
    for (int t = 0; t < 4; ++t) {
        bf16x8 ah = *(const bf16x8*)&Ph[t * 16 + c16][q * 8];
        bf16x8 al = *(const bf16x8*)&Pl[t * 16 + c16][q * 8];
        acc[t] = __builtin_amdgcn_mfma_f32_16x16x32_bf16(ah, W0H, acc[t], 0, 0, 0);
        acc[t] = __builtin_amdgcn_mfma_f32_16x16x32_bf16(al, W0H, acc[t], 0, 0, 0);
        acc[t] = __builtin_amdgcn_mfma_f32_16x16x32_bf16(ah, W0L, acc[t], 0, 0, 0);
    }
    // no relu after layer 0; split-store h0 -> Ha pair
    #pragma unroll
    for (int t = 0; t < 4; ++t)
        #pragma unroll
        for (int r = 0; r < 4; ++r) {
            unsigned short h, l; split2(acc[t][r], h, l);
            Hah[t * 16 + q * 4 + r][n] = h;
            Hal[t * 16 + q * 4 + r][n] = l;
        }
    __syncthreads();   // also fences last pssm reads before Hb overlay writes

    // ---- layer 1: Ha -> Hb (relu) ----
    {
        f32x4 a1[4];
        #pragma unroll
        for (int t = 0; t < 4; ++t) {
            a1[t] = (f32x4){be_n, be_n, be_n, be_n};
            #pragma unroll
            for (int kk = 0; kk < 2; ++kk) {
                bf16x8 ah = *(const bf16x8*)&Hah[t * 16 + c16][kk * 32 + q * 8];
                bf16x8 al = *(const bf16x8*)&Hal[t * 16 + c16][kk * 32 + q * 8];
                a1[t] = __builtin_amdgcn_mfma_f32_16x16x32_bf16(ah, WeH[kk], a1[t], 0, 0, 0);
                a1[t] = __builtin_amdgcn_mfma_f32_16x16x32_bf16(al, WeH[kk], a1[t], 0, 0, 0);
                a1[t] = __builtin_amdgcn_mfma_f32_16x16x32_bf16(ah, WeL[kk], a1[t], 0, 0, 0);
            }
        }
        #pragma unroll
        for (int t = 0; t < 4; ++t)
            #pragma unroll
            for (int r = 0; r < 4; ++r) {
                unsigned short h, l; split2(fmaxf(a1[t][r], 0.f), h, l);
                Hbh[t * 16 + q * 4 + r][n] = h;
                Hbl[t * 16 + q * 4 + r][n] = l;
            }
        __syncthreads();
    }
    // ---- layer 2: Hb -> Ha (relu) ----
    {
        f32x4 a2[4];
        #pragma unroll
        for (int t = 0; t < 4; ++t) {
            a2[t] = (f32x4){be_n, be_n, be_n, be_n};
            #pragma unroll
            for (int kk = 0; kk < 2; ++kk) {
                bf16x8 ah = *(const bf16x8*)&Hbh[t * 16 + c16][kk * 32 + q * 8];
                bf16x8 al = *(const bf16x8*)&Hbl[t * 16 + c16][kk * 32 + q * 8];
                a2[t] = __builtin_amdgcn_mfma_f32_16x16x32_bf16(ah, WeH[kk], a2[t], 0, 0, 0);
                a2[t] = __builtin_amdgcn_mfma_f32_16x16x32_bf16(al, WeH[kk], a2[t], 0, 0, 0);
                a2[t] = __builtin_amdgcn_mfma_f32_16x16x32_bf16(ah, WeL[kk], a2[t], 0, 0, 0);
            }
        }
        #pragma unroll
        for (int t = 0; t < 4; ++t)
            #pragma unroll
            for (int r = 0; r < 4; ++r) {
                unsigned short h, l; split2(fmaxf(a2[t][r], 0.f), h, l);
                Hah[t * 16 + q * 4 + r][n] = h;
                Hal[t * 16 + q * 4 + r][n] = l;
            }
        __syncthreads();
    }

    // ---- head: wave wv does M-tile wv; B = W1 pair (cols padded to 16) ----
    {
        f32x4 ah4 = (f32x4){b1h, b1h, b1h, b1h};
        #pragma unroll
        for (int kk = 0; kk < 2; ++kk) {
            bf16x8 ah = *(const bf16x8*)&Hah[wv * 16 + c16][kk * 32 + q * 8];
            bf16x8 al = *(const bf16x8*)&Hal[wv * 16 + c16][kk * 32 + q * 8];
            ah4 = __builtin_amdgcn_mfma_f32_16x16x32_bf16(ah, W1H[kk], ah4, 0, 0, 0);
            ah4 = __builtin_amdgcn_mfma_f32_16x16x32_bf16(al, W1H[kk], ah4, 0, 0, 0);
            ah4 = __builtin_amdgcn_mfma_f32_16x16x32_bf16(ah, W1L[kk], ah4, 0, 0, 0);
        }
        if (c16 < 9) {
            #pragma unroll
            for (int r = 0; r < 4; ++r) {
                int pos = m0 + wv * 16 + q * 4 + r;
                int l = pos >> 8, b = pos & 255;
                srf_t[(l * 9 + c16) * 256 + b] = ah4[r];
            }
        }
    }
}

// ---------- pNeRF phase 1 ----------
__global__ __launch_bounds__(64) void extend_kernel(
    const float* __restrict__ srf_t, float* __restrict__ fragbuf) {
    int frag = blockIdx.x >> 2;
    int bb   = ((blockIdx.x & 3) << 6) + threadIdx.x;

    float3 A  = make_float3(-0.70710678118654752f, 1.22474487139158905f, 0.f);
    float3 Bv = make_float3(-1.41421356237309505f, 0.f, 0.f);
    float3 C  = make_float3(0.f, 0.f, 0.f);

    float ct[9];
    #pragma unroll
    for (int m = 0; m < 9; ++m)
        ct[m] = srf_t[((frag * 32) * 9 + m) * 256 + bb];

    for (int ll = 0; ll < 32; ++ll) {
        float nct[9];
        if (ll < 31) {
            #pragma unroll
            for (int m = 0; m < 9; ++m)
                nct[m] = srf_t[((frag * 32 + ll + 1) * 9 + m) * 256 + bb];
        } else {
            #pragma unroll
            for (int m = 0; m < 9; ++m) nct[m] = 0.f;
        }
        #pragma unroll
        for (int s3 = 0; s3 < 3; ++s3) {
            float3 bc, nn, m3;
            nerf_frame(A, Bv, C, bc, nn, m3);
            float3 d = nerf_place(C, bc, m3, nn,
                                  ct[3 * s3 + 0], ct[3 * s3 + 1], ct[3 * s3 + 2]);
            int row = frag * 96 + ll * 3 + s3;
            fragbuf[(row * 3 + 0) * 256 + bb] = d.x;
            fragbuf[(row * 3 + 1) * 256 + bb] = d.y;
            fragbuf[(row * 3 + 2) * 256 + bb] = d.z;
            A = Bv; Bv = C; C = d;
        }
        #pragma unroll
        for (int m = 0; m < 9; ++m) ct[m] = nct[m];
    }
}

// ---------- pNeRF phase 2a: fragment carry chain ----------
__global__ __launch_bounds__(256) void carry_kernel(
    const float* __restrict__ fragbuf, float* __restrict__ frames) {
    int bb = threadIdx.x;
    float3 A  = make_float3(-0.70710678118654752f, 1.22474487139158905f, 0.f);
    float3 Bv = make_float3(-1.41421356237309505f, 0.f, 0.f);
    float3 C  = make_float3(0.f, 0.f, 0.f);

    float fr[9];
    #pragma unroll
    for (int t = 0; t < 3; ++t)
        #pragma unroll
        for (int c = 0; c < 3; ++c)
            fr[t * 3 + c] = fragbuf[((93 + t) * 3 + c) * 256 + bb];

    for (int frag = 0; frag < 32; ++frag) {
        float nfr[9];
        if (frag < 31) {
            #pragma unroll
            for (int t = 0; t < 3; ++t)
                #pragma unroll
                for (int c = 0; c < 3; ++c)
                    nfr[t * 3 + c] =
                        fragbuf[(((frag + 1) * 96 + 93 + t) * 3 + c) * 256 + bb];
        } else {
            #pragma unroll
            for (int m = 0; m < 9; ++m) nfr[m] = 0.f;
        }
        float3 bc, nn, m3;
        nerf_frame(A, Bv, C, bc, nn, m3);

        frames[(frag * 12 + 0)  * 256 + bb] = bc.x;
        frames[(frag * 12 + 1)  * 256 + bb] = bc.y;
        frames[(frag * 12 + 2)  * 256 + bb] = bc.z;
        frames[(frag * 12 + 3)  * 256 + bb] = m3.x;
        frames[(frag * 12 + 4)  * 256 + bb] = m3.y;
        frames[(frag * 12 + 5)  * 256 + bb] = m3.z;
        frames[(frag * 12 + 6)  * 256 + bb] = nn.x;
        frames[(frag * 12 + 7)  * 256 + bb] = nn.y;
        frames[(frag * 12 + 8)  * 256 + bb] = nn.z;
        frames[(frag * 12 + 9)  * 256 + bb] = C.x;
        frames[(frag * 12 + 10) * 256 + bb] = C.y;
        frames[(frag * 12 + 11) * 256 + bb] = C.z;

        float3 y[3];
        #pragma unroll
        for (int t = 0; t < 3; ++t)
            y[t] = nerf_place(C, bc, m3, nn, fr[t * 3], fr[t * 3 + 1], fr[t * 3 + 2]);
        A = y[0]; Bv = y[1]; C = y[2];
        #pragma unroll
        for (int m = 0; m < 9; ++m) fr[m] = nfr[m];
    }
}

// ---------- pNeRF phase 2b: apply frames ----------
__global__ __launch_bounds__(256) void apply_kernel(
    const float* __restrict__ fragbuf, const float* __restrict__ frames,
    float* __restrict__ out) {
    int bb   = threadIdx.x;
    int row  = blockIdx.x;
    int frag = row / 96;

    float fx = fragbuf[(row * 3 + 0) * 256 + bb];
    float fy = fragbuf[(row * 3 + 1) * 256 + bb];
    float fz = fragbuf[(row * 3 + 2) * 256 + bb];

    float bcx = frames[(frag * 12 + 0)  * 256 + bb];
    float bcy = frames[(frag * 12 + 1)  * 256 + bb];
    float bcz = frames[(frag * 12 + 2)  * 256 + bb];
    float mx  = frames[(frag * 12 + 3)  * 256 + bb];
    float my  = frames[(frag * 12 + 4)  * 256 + bb];
    float mz  = frames[(frag * 12 + 5)  * 256 + bb];
    float nx  = frames[(frag * 12 + 6)  * 256 + bb];
    float ny  = frames[(frag * 12 + 7)  * 256 + bb];
    float nz  = frames[(frag * 12 + 8)  * 256 + bb];
    float cx  = frames[(frag * 12 + 9)  * 256 + bb];
    float cy  = frames[(frag * 12 + 10) * 256 + bb];
    float cz  = frames[(frag * 12 + 11) * 256 + bb];

    out[(row * 256 + bb) * 3 + 0] = cx + bcx * fx + mx * fy + nx * fz;
    out[(row * 256 + bb) * 3 + 1] = cy + bcy * fx + my * fy + ny * fz;
    out[(row * 256 + bb) * 3 + 2] = cz + bcz * fx + mz * fy + nz * fz;
}

// ---------- host launch ----------
extern "C" void kernel_launch(void* const* d_in, const int* in_sizes, int n_in,
                              void* d_out, int out_size, void* d_ws, size_t ws_size,
                              hipStream_t stream) {
    const int*   seq        = (const int*)d_in[0];
    const int*   kmer       = (const int*)d_in[1];
    const float* pssm       = (const float*)d_in[2];
    const float* seq_embed  = (const float*)d_in[4];
    const float* kmer_embed = (const float*)d_in[5];
    const float* W0         = (const float*)d_in[6];
    const float* b0         = (const float*)d_in[7];
    const float* We         = (const float*)d_in[8];
    const float* be         = (const float*)d_in[9];
    const float* W1         = (const float*)d_in[10];
    const float* b1         = (const float*)d_in[11];

    float* ws      = (float*)d_ws;
    float* kmerT   = ws;                       // 10648*64 = 681472
    float* seqT    = kmerT + 681472;           // 20*64    = 1280
    float* srf_t   = seqT + 1280;              // 1024*9*256 = 2359296
    float* fragbuf = srf_t + 2359296;          // 3072*3*256 = 2359296
    float* frames  = fragbuf + 2359296;        // 32*12*256  = 98304
    float* out     = (float*)d_out;

    hipLaunchKernelGGL(seq_table_kernel, dim3(20), dim3(64), 0, stream,
                       seq_embed, W0, b0, seqT);
    hipLaunchKernelGGL(kmer_table_kernel, dim3(242), dim3(256), 0, stream,
                       kmer_embed, W0, kmerT);
    hipLaunchKernelGGL(mlp_kernel, dim3(4096), dim3(256), 0, stream,
                       seq, kmer, pssm, seqT, kmerT, W0, We, be, W1, b1, srf_t);
    hipLaunchKernelGGL(extend_kernel, dim3(128), dim3(64), 0, stream,
                       srf_t, fragbuf);
    hipLaunchKernelGGL(carry_kernel, dim3(1), dim3(256), 0, stream,
                       fragbuf, frames);
    hipLaunchKernelGGL(apply_kernel, dim3(3072), dim3(256), 0, stream,
                       fragbuf, frames, out);
}